// Round 3
// baseline (557.179 us; speedup 1.0000x reference)
//
#include <hip/hip_runtime.h>
#include <cstdint>
#include <cstddef>

// Instant-NGP hash-grid encode, level-sequential two-phase version.
//
// R1 post-mortem: fused all-levels-per-thread kernel fetched 748 MB from HBM
// (expected ~27) because the ~14.5 MB multi-level table working set thrashes
// the 4 MB per-XCD L2 while the 131 MB output stream evicts table lines.
//
// Fix: temporal separation of levels.
//   Phase 1a: dense levels 0-4 fused (tables total 2.65 MB -> fits L2),
//             write ws[lv][N][2] coalesced, nontemporal.
//   Phase 1b: hashed levels 5..15 as blockIdx.y slices; while a slice runs,
//             its single 4 MB table is the only gather working set -> L2-hot.
//             Masked levels exit immediately.
//   Phase 2:  transpose ws[16][N][2] -> out[N][32], applying the mask
//             (masked levels contribute zeros without reading poisoned ws).
// Nontemporal loads/stores on all streaming traffic keep tables L2-resident.
// R2 fix: __builtin_nontemporal_* needs clang ext_vector_type, not HIP float2/4.

namespace {

constexpr int      kNLevels = 16;
constexpr uint32_t kT       = 1u << 19;             // 524288 entries / level
constexpr uint32_t kP1      = 2654435761u;           // tcnn hash primes (y, z)
constexpr uint32_t kP2      = 805459861u;

typedef float v2f __attribute__((ext_vector_type(2)));
typedef float v4f __attribute__((ext_vector_type(4)));

// floor(16 * scale^lv) + 1, scale = exp((ln 2048 - ln 16)/15)
__device__ constexpr int kRes[kNLevels] = {
    17, 23, 31, 43, 59, 81, 112, 154, 213, 295, 407, 562, 777, 1073, 1483, 2049
};

__device__ inline void corner_setup(float px, float py, float pz, int res,
                                    int& cx, int& cy, int& cz,
                                    float& wx, float& wy, float& wz) {
    const float s = (float)(res - 1);
    const float fx = px * s, fy = py * s, fz = pz * s;
    cx = (int)floorf(fx); cy = (int)floorf(fy); cz = (int)floorf(fz);
    cx = min(max(cx, 0), res - 2);
    cy = min(max(cy, 0), res - 2);
    cz = min(max(cz, 0), res - 2);
    wx = fx - (float)cx; wy = fy - (float)cy; wz = fz - (float)cz;
}

// ---------- Phase 1a: dense levels 0..4 fused ----------
__global__ __launch_bounds__(256) void dense_levels_kernel(
    const float* __restrict__ x, const float* __restrict__ table,
    const float* __restrict__ mask, float* __restrict__ ws, int n)
{
    const int p = blockIdx.x * blockDim.x + threadIdx.x;
    if (p >= n) return;
    const float px = __builtin_nontemporal_load(x + 3 * p + 0);
    const float py = __builtin_nontemporal_load(x + 3 * p + 1);
    const float pz = __builtin_nontemporal_load(x + 3 * p + 2);

#pragma unroll
    for (int lv = 0; lv < 5; ++lv) {
        const float m0 = mask[2 * lv], m1 = mask[2 * lv + 1];
        if (m0 == 0.0f && m1 == 0.0f) continue;
        const int res = kRes[lv];
        int cx, cy, cz; float wx, wy, wz;
        corner_setup(px, py, pz, res, cx, cy, cz, wx, wy, wz);
        const float ux = 1.0f - wx, uy = 1.0f - wy, uz = 1.0f - wz;
        const float* __restrict__ tbl = table + (size_t)lv * (size_t)(kT * 2);
        float r0 = 0.0f, r1 = 0.0f;
#pragma unroll
        for (int c = 0; c < 8; ++c) {
            const int dx = c & 1, dy = (c >> 1) & 1, dz = (c >> 2) & 1;
            const uint32_t idx =
                (uint32_t)((cx + dx) + res * ((cy + dy) + res * (cz + dz)));
            const v2f v = *(const v2f*)(tbl + 2u * idx);
            const float w = (dx ? wx : ux) * (dy ? wy : uy) * (dz ? wz : uz);
            r0 = fmaf(v.x, w, r0);
            r1 = fmaf(v.y, w, r1);
        }
        v2f o; o.x = r0; o.y = r1;
        __builtin_nontemporal_store(o, (v2f*)(ws + ((size_t)lv * n + p) * 2));
    }
}

// ---------- Phase 1b: hashed levels 5..15, one blockIdx.y slice per level ----
__global__ __launch_bounds__(256) void hashed_level_kernel(
    const float* __restrict__ x, const float* __restrict__ table,
    const float* __restrict__ mask, float* __restrict__ ws, int n)
{
    const int lv = 5 + blockIdx.y;
    const float m0 = mask[2 * lv], m1 = mask[2 * lv + 1];
    if (m0 == 0.0f && m1 == 0.0f) return;   // masked level: whole slice exits

    const int p = blockIdx.x * blockDim.x + threadIdx.x;
    if (p >= n) return;
    const float px = __builtin_nontemporal_load(x + 3 * p + 0);
    const float py = __builtin_nontemporal_load(x + 3 * p + 1);
    const float pz = __builtin_nontemporal_load(x + 3 * p + 2);

    const int res = kRes[lv];
    int cx, cy, cz; float wx, wy, wz;
    corner_setup(px, py, pz, res, cx, cy, cz, wx, wy, wz);
    const float ux = 1.0f - wx, uy = 1.0f - wy, uz = 1.0f - wz;
    const float* __restrict__ tbl = table + (size_t)lv * (size_t)(kT * 2);

    float r0 = 0.0f, r1 = 0.0f;
#pragma unroll
    for (int c = 0; c < 8; ++c) {
        const int dx = c & 1, dy = (c >> 1) & 1, dz = (c >> 2) & 1;
        const uint32_t idx =
            (((uint32_t)(cx + dx)) ^ ((uint32_t)(cy + dy) * kP1)
                                   ^ ((uint32_t)(cz + dz) * kP2)) & (kT - 1u);
        const v2f v = *(const v2f*)(tbl + 2u * idx);
        const float w = (dx ? wx : ux) * (dy ? wy : uy) * (dz ? wz : uz);
        r0 = fmaf(v.x, w, r0);
        r1 = fmaf(v.y, w, r1);
    }
    v2f o; o.x = r0; o.y = r1;
    __builtin_nontemporal_store(o, (v2f*)(ws + ((size_t)lv * n + p) * 2));
}

// ---------- Phase 2: transpose ws[16][N][2] -> out[N][32], apply mask -------
__global__ __launch_bounds__(256) void gather_out_kernel(
    const float* __restrict__ ws, const float* __restrict__ mask,
    float* __restrict__ out, int n)
{
    const int p = blockIdx.x * blockDim.x + threadIdx.x;
    if (p >= n) return;

    v4f o[8];
#pragma unroll
    for (int lv = 0; lv < kNLevels; ++lv) {
        const float m0 = mask[2 * lv], m1 = mask[2 * lv + 1];
        float r0 = 0.0f, r1 = 0.0f;
        if (m0 != 0.0f || m1 != 0.0f) {
            const v2f v = __builtin_nontemporal_load(
                (const v2f*)(ws + ((size_t)lv * n + p) * 2));
            r0 = v.x * m0;
            r1 = v.y * m1;
        }
        if (lv & 1) { o[lv >> 1].z = r0; o[lv >> 1].w = r1; }
        else        { o[lv >> 1].x = r0; o[lv >> 1].y = r1; }
    }
    v4f* __restrict__ op = (v4f*)(out + (size_t)p * 32);
#pragma unroll
    for (int i = 0; i < 8; ++i) __builtin_nontemporal_store(o[i], op + i);
}

// ---------- Fallback (R1 fused kernel) if ws is too small -------------------
__global__ __launch_bounds__(256) void fused_kernel(
    const float* __restrict__ x, const float* __restrict__ table,
    const float* __restrict__ mask, float* __restrict__ out, int n)
{
    const int p = blockIdx.x * blockDim.x + threadIdx.x;
    if (p >= n) return;
    const float px = x[3 * p + 0], py = x[3 * p + 1], pz = x[3 * p + 2];
    v4f o[8];
#pragma unroll
    for (int lv = 0; lv < kNLevels; ++lv) {
        const float m0 = mask[2 * lv], m1 = mask[2 * lv + 1];
        float r0 = 0.0f, r1 = 0.0f;
        if (m0 != 0.0f || m1 != 0.0f) {
            const int res = kRes[lv];
            const bool dense = ((long long)res * res * res) <= (long long)kT;
            int cx, cy, cz; float wx, wy, wz;
            corner_setup(px, py, pz, res, cx, cy, cz, wx, wy, wz);
            const float ux = 1.0f - wx, uy = 1.0f - wy, uz = 1.0f - wz;
            const float* __restrict__ tbl = table + (size_t)lv * (size_t)(kT * 2);
#pragma unroll
            for (int c = 0; c < 8; ++c) {
                const int dx = c & 1, dy = (c >> 1) & 1, dz = (c >> 2) & 1;
                const int ix = cx + dx, iy = cy + dy, iz = cz + dz;
                uint32_t idx;
                if (dense) idx = (uint32_t)(ix + res * (iy + res * iz));
                else idx = (((uint32_t)ix) ^ ((uint32_t)iy * kP1)
                                           ^ ((uint32_t)iz * kP2)) & (kT - 1u);
                const v2f v = *(const v2f*)(tbl + 2u * idx);
                const float w = (dx ? wx : ux) * (dy ? wy : uy) * (dz ? wz : uz);
                r0 = fmaf(v.x, w, r0);
                r1 = fmaf(v.y, w, r1);
            }
            r0 *= m0; r1 *= m1;
        }
        if (lv & 1) { o[lv >> 1].z = r0; o[lv >> 1].w = r1; }
        else        { o[lv >> 1].x = r0; o[lv >> 1].y = r1; }
    }
    v4f* __restrict__ op = (v4f*)(out + (size_t)p * 32);
#pragma unroll
    for (int i = 0; i < 8; ++i) op[i] = o[i];
}

}  // namespace

extern "C" void kernel_launch(void* const* d_in, const int* in_sizes, int n_in,
                              void* d_out, int out_size, void* d_ws, size_t ws_size,
                              hipStream_t stream) {
    const float* x     = (const float*)d_in[0];
    const float* table = (const float*)d_in[1];
    const float* mask  = (const float*)d_in[2];
    float*       out   = (float*)d_out;

    const int n = in_sizes[0] / 3;  // 1048576 points
    const int block = 256;
    const int gx = (n + block - 1) / block;

    const size_t ws_needed = (size_t)kNLevels * (size_t)n * 2 * sizeof(float);
    if (ws_size >= ws_needed) {
        float* ws = (float*)d_ws;
        dense_levels_kernel<<<gx, block, 0, stream>>>(x, table, mask, ws, n);
        dim3 grid_h(gx, kNLevels - 5);  // levels 5..15, masked slices exit fast
        hashed_level_kernel<<<grid_h, block, 0, stream>>>(x, table, mask, ws, n);
        gather_out_kernel<<<gx, block, 0, stream>>>(ws, mask, out, n);
    } else {
        fused_kernel<<<gx, block, 0, stream>>>(x, table, mask, out, n);
    }
}

// Round 4
// 354.620 us; speedup vs baseline: 1.5712x; 1.5712x over previous
//
#include <hip/hip_runtime.h>
#include <cstdint>
#include <cstddef>

// Instant-NGP hash-grid encode, level-sliced two-phase version (R4).
//
// R1: fused kernel = 247 us, 748 MB L2-fill (multi-level table thrash).
// R3: two-phase with nontemporal OUT stores = 533 MB WRITE_SIZE (nt defeats
//     L2 write-combining of the stride-128 16B-per-lane store pattern).
// R4 fixes:
//  - nt ONLY on full-line ws stores (64 lanes x 8 B contiguous) and on
//    streaming ws reads; plain stores for out (L2 merges partials -> 131 MB).
//  - single y-sliced phase-1 kernel: blockIdx.y = level, masked slices exit.
//    Blocks dispatch x-fastest, so levels run near-sequentially -> each 4 MB
//    hashed table is L2-resident while its slice runs.
//  - dense levels: dx=0/1 corners are adjacent table entries -> one paired
//    16 B load (two adjacent v2f loads; the vectorizer merges to dwordx4).

namespace {

constexpr int      kNLevels = 16;
constexpr uint32_t kT       = 1u << 19;             // 524288 entries / level
constexpr uint32_t kP1      = 2654435761u;           // tcnn hash primes (y, z)
constexpr uint32_t kP2      = 805459861u;

typedef float v2f __attribute__((ext_vector_type(2)));
typedef float v4f __attribute__((ext_vector_type(4)));

// floor(16 * scale^lv) + 1, scale = exp((ln 2048 - ln 16)/15)
__device__ constexpr int kRes[kNLevels] = {
    17, 23, 31, 43, 59, 81, 112, 154, 213, 295, 407, 562, 777, 1073, 1483, 2049
};
// dense iff res^3 <= T  <=>  res <= 80 (80^3 = 512000 <= 524288 < 81^3)

__device__ inline void corner_setup(float px, float py, float pz, int res,
                                    int& cx, int& cy, int& cz,
                                    float& wx, float& wy, float& wz) {
    const float s = (float)(res - 1);
    const float fx = px * s, fy = py * s, fz = pz * s;
    cx = (int)floorf(fx); cy = (int)floorf(fy); cz = (int)floorf(fz);
    cx = min(max(cx, 0), res - 2);
    cy = min(max(cy, 0), res - 2);
    cz = min(max(cz, 0), res - 2);
    wx = fx - (float)cx; wy = fy - (float)cy; wz = fz - (float)cz;
}

// ---------- Phase 1: one level per blockIdx.y slice -------------------------
__global__ __launch_bounds__(256) void level_kernel(
    const float* __restrict__ x, const float* __restrict__ table,
    const float* __restrict__ mask, float* __restrict__ ws, int n)
{
    const int lv = blockIdx.y;
    const float m0 = mask[2 * lv], m1 = mask[2 * lv + 1];
    if (m0 == 0.0f && m1 == 0.0f) return;   // masked level: slice exits

    const int p = blockIdx.x * blockDim.x + threadIdx.x;
    if (p >= n) return;
    const float px = x[3 * p + 0];
    const float py = x[3 * p + 1];
    const float pz = x[3 * p + 2];

    const int res = kRes[lv];
    int cx, cy, cz; float wx, wy, wz;
    corner_setup(px, py, pz, res, cx, cy, cz, wx, wy, wz);
    const float ux = 1.0f - wx, uy = 1.0f - wy, uz = 1.0f - wz;
    const float* __restrict__ tbl = table + (size_t)lv * (size_t)(kT * 2);

    float r0 = 0.0f, r1 = 0.0f;
    if (res <= 80) {
        // dense grid: corners (dx=0,1) are adjacent entries -> paired loads
#pragma unroll
        for (int c = 0; c < 4; ++c) {
            const int dy = c & 1, dz = (c >> 1) & 1;
            const uint32_t idx0 =
                (uint32_t)(cx + res * ((cy + dy) + res * (cz + dz)));
            const v2f a = *(const v2f*)(tbl + 2u * idx0);
            const v2f b = *(const v2f*)(tbl + 2u * idx0 + 2);
            const float wyz = (dy ? wy : uy) * (dz ? wz : uz);
            const float w0 = ux * wyz, w1 = wx * wyz;
            r0 = fmaf(a.x, w0, fmaf(b.x, w1, r0));
            r1 = fmaf(a.y, w0, fmaf(b.y, w1, r1));
        }
    } else {
        // hashed level
#pragma unroll
        for (int c = 0; c < 8; ++c) {
            const int dx = c & 1, dy = (c >> 1) & 1, dz = (c >> 2) & 1;
            const uint32_t idx =
                (((uint32_t)(cx + dx)) ^ ((uint32_t)(cy + dy) * kP1)
                                       ^ ((uint32_t)(cz + dz) * kP2)) & (kT - 1u);
            const v2f v = *(const v2f*)(tbl + 2u * idx);
            const float w = (dx ? wx : ux) * (dy ? wy : uy) * (dz ? wz : uz);
            r0 = fmaf(v.x, w, r0);
            r1 = fmaf(v.y, w, r1);
        }
    }
    v2f o; o.x = r0; o.y = r1;
    // full-line coalesced (64 lanes x 8 B contiguous): nt is safe here
    __builtin_nontemporal_store(o, (v2f*)(ws + ((size_t)lv * n + p) * 2));
}

// ---------- Phase 2: transpose ws[16][N][2] -> out[N][32], apply mask -------
__global__ __launch_bounds__(256) void gather_out_kernel(
    const float* __restrict__ ws, const float* __restrict__ mask,
    float* __restrict__ out, int n)
{
    const int p = blockIdx.x * blockDim.x + threadIdx.x;
    if (p >= n) return;

    v4f o[8];
#pragma unroll
    for (int lv = 0; lv < kNLevels; ++lv) {
        const float m0 = mask[2 * lv], m1 = mask[2 * lv + 1];
        float r0 = 0.0f, r1 = 0.0f;
        if (m0 != 0.0f || m1 != 0.0f) {
            const v2f v = __builtin_nontemporal_load(
                (const v2f*)(ws + ((size_t)lv * n + p) * 2));
            r0 = v.x * m0;
            r1 = v.y * m1;
        }
        if (lv & 1) { o[lv >> 1].z = r0; o[lv >> 1].w = r1; }
        else        { o[lv >> 1].x = r0; o[lv >> 1].y = r1; }
    }
    v4f* __restrict__ op = (v4f*)(out + (size_t)p * 32);
#pragma unroll
    for (int i = 0; i < 8; ++i) op[i] = o[i];   // plain stores: L2 merges
}

// ---------- Fallback (R1 fused kernel) if ws is too small -------------------
__global__ __launch_bounds__(256) void fused_kernel(
    const float* __restrict__ x, const float* __restrict__ table,
    const float* __restrict__ mask, float* __restrict__ out, int n)
{
    const int p = blockIdx.x * blockDim.x + threadIdx.x;
    if (p >= n) return;
    const float px = x[3 * p + 0], py = x[3 * p + 1], pz = x[3 * p + 2];
    v4f o[8];
#pragma unroll
    for (int lv = 0; lv < kNLevels; ++lv) {
        const float m0 = mask[2 * lv], m1 = mask[2 * lv + 1];
        float r0 = 0.0f, r1 = 0.0f;
        if (m0 != 0.0f || m1 != 0.0f) {
            const int res = kRes[lv];
            const bool dense = ((long long)res * res * res) <= (long long)kT;
            int cx, cy, cz; float wx, wy, wz;
            corner_setup(px, py, pz, res, cx, cy, cz, wx, wy, wz);
            const float ux = 1.0f - wx, uy = 1.0f - wy, uz = 1.0f - wz;
            const float* __restrict__ tbl = table + (size_t)lv * (size_t)(kT * 2);
#pragma unroll
            for (int c = 0; c < 8; ++c) {
                const int dx = c & 1, dy = (c >> 1) & 1, dz = (c >> 2) & 1;
                const int ix = cx + dx, iy = cy + dy, iz = cz + dz;
                uint32_t idx;
                if (dense) idx = (uint32_t)(ix + res * (iy + res * iz));
                else idx = (((uint32_t)ix) ^ ((uint32_t)iy * kP1)
                                           ^ ((uint32_t)iz * kP2)) & (kT - 1u);
                const v2f v = *(const v2f*)(tbl + 2u * idx);
                const float w = (dx ? wx : ux) * (dy ? wy : uy) * (dz ? wz : uz);
                r0 = fmaf(v.x, w, r0);
                r1 = fmaf(v.y, w, r1);
            }
            r0 *= m0; r1 *= m1;
        }
        if (lv & 1) { o[lv >> 1].z = r0; o[lv >> 1].w = r1; }
        else        { o[lv >> 1].x = r0; o[lv >> 1].y = r1; }
    }
    v4f* __restrict__ op = (v4f*)(out + (size_t)p * 32);
#pragma unroll
    for (int i = 0; i < 8; ++i) op[i] = o[i];
}

}  // namespace

extern "C" void kernel_launch(void* const* d_in, const int* in_sizes, int n_in,
                              void* d_out, int out_size, void* d_ws, size_t ws_size,
                              hipStream_t stream) {
    const float* x     = (const float*)d_in[0];
    const float* table = (const float*)d_in[1];
    const float* mask  = (const float*)d_in[2];
    float*       out   = (float*)d_out;

    const int n = in_sizes[0] / 3;  // 1048576 points
    const int block = 256;
    const int gx = (n + block - 1) / block;

    const size_t ws_needed = (size_t)kNLevels * (size_t)n * 2 * sizeof(float);
    if (ws_size >= ws_needed) {
        float* ws = (float*)d_ws;
        dim3 grid1(gx, kNLevels);       // one y-slice per level
        level_kernel<<<grid1, block, 0, stream>>>(x, table, mask, ws, n);
        gather_out_kernel<<<gx, block, 0, stream>>>(ws, mask, out, n);
    } else {
        fused_kernel<<<gx, block, 0, stream>>>(x, table, mask, out, n);
    }
}

// Round 5
// 350.719 us; speedup vs baseline: 1.5887x; 1.0111x over previous
//
#include <hip/hip_runtime.h>
#include <cstdint>
#include <cstddef>

// Instant-NGP hash-grid encode, R5: hashed-only phase 1 + dense-recompute phase 2.
//
// History: R1 fused = 247 us kernel (748 MB L2 thrash from hashed tables).
// R4 two-phase = 210 us kernels; level_kernel TA-bound (~64M divergent gather
// addresses ~= 1 addr/cy/CU). Dense levels cost TA like hashed ones but their
// tables (2.65 MB total) never thrash L2 -> recompute them in phase 2 instead
// of round-tripping through ws.
//  - Phase 1: hashed levels (res>80) as blockIdx.y slices (lv 5..15, masked
//    slices exit). Each slice's 4 MB table is L2-resident while it runs.
//    ws[11][N][2], full-line nt stores.
//  - Phase 2: recompute dense levels 0..4 (x-corner pair = adjacent 16 B ->
//    single unaligned dwordx4 load, halves dense TA), read hashed results
//    from ws (nt), apply mask, write out[N][32] with plain stores (L2 merges
//    the stride-128 16B partials; nt here caused R3's 533 MB writes).

namespace {

constexpr int      kNLevels = 16;
constexpr uint32_t kT       = 1u << 19;             // 524288 entries / level
constexpr uint32_t kP1      = 2654435761u;           // tcnn hash primes (y, z)
constexpr uint32_t kP2      = 805459861u;

typedef float v2f __attribute__((ext_vector_type(2)));
typedef float v4f __attribute__((ext_vector_type(4)));

// floor(16 * scale^lv) + 1, scale = exp((ln 2048 - ln 16)/15)
__device__ constexpr int kRes[kNLevels] = {
    17, 23, 31, 43, 59, 81, 112, 154, 213, 295, 407, 562, 777, 1073, 1483, 2049
};
// dense iff res^3 <= T  <=>  res <= 80; levels 0..4 dense, 5..15 hashed.

__device__ inline void corner_setup(float px, float py, float pz, int res,
                                    int& cx, int& cy, int& cz,
                                    float& wx, float& wy, float& wz) {
    const float s = (float)(res - 1);
    const float fx = px * s, fy = py * s, fz = pz * s;
    cx = (int)floorf(fx); cy = (int)floorf(fy); cz = (int)floorf(fz);
    cx = min(max(cx, 0), res - 2);
    cy = min(max(cy, 0), res - 2);
    cz = min(max(cz, 0), res - 2);
    wx = fx - (float)cx; wy = fy - (float)cy; wz = fz - (float)cz;
}

// ---------- Phase 1: hashed levels 5..15, one blockIdx.y slice per level ----
__global__ __launch_bounds__(256) void hashed_level_kernel(
    const float* __restrict__ x, const float* __restrict__ table,
    const float* __restrict__ mask, float* __restrict__ ws, int n)
{
    const int lv = 5 + blockIdx.y;
    const float m0 = mask[2 * lv], m1 = mask[2 * lv + 1];
    if (m0 == 0.0f && m1 == 0.0f) return;   // masked level: slice exits

    const int p = blockIdx.x * blockDim.x + threadIdx.x;
    if (p >= n) return;
    const float px = x[3 * p + 0];
    const float py = x[3 * p + 1];
    const float pz = x[3 * p + 2];

    const int res = kRes[lv];
    int cx, cy, cz; float wx, wy, wz;
    corner_setup(px, py, pz, res, cx, cy, cz, wx, wy, wz);
    const float ux = 1.0f - wx, uy = 1.0f - wy, uz = 1.0f - wz;
    const float* __restrict__ tbl = table + (size_t)lv * (size_t)(kT * 2);

    float r0 = 0.0f, r1 = 0.0f;
#pragma unroll
    for (int c = 0; c < 8; ++c) {
        const int dx = c & 1, dy = (c >> 1) & 1, dz = (c >> 2) & 1;
        const uint32_t idx =
            (((uint32_t)(cx + dx)) ^ ((uint32_t)(cy + dy) * kP1)
                                   ^ ((uint32_t)(cz + dz) * kP2)) & (kT - 1u);
        const v2f v = *(const v2f*)(tbl + 2u * idx);
        const float w = (dx ? wx : ux) * (dy ? wy : uy) * (dz ? wz : uz);
        r0 = fmaf(v.x, w, r0);
        r1 = fmaf(v.y, w, r1);
    }
    v2f o; o.x = r0; o.y = r1;
    // full-line coalesced (64 lanes x 8 B contiguous): nt is safe here
    __builtin_nontemporal_store(
        o, (v2f*)(ws + ((size_t)(lv - 5) * n + p) * 2));
}

// ---------- Phase 2: dense recompute + hashed readback -> out[N][32] --------
__global__ __launch_bounds__(256) void gather_out_kernel(
    const float* __restrict__ x, const float* __restrict__ table,
    const float* __restrict__ ws, const float* __restrict__ mask,
    float* __restrict__ out, int n)
{
    const int p = blockIdx.x * blockDim.x + threadIdx.x;
    if (p >= n) return;
    const float px = x[3 * p + 0];
    const float py = x[3 * p + 1];
    const float pz = x[3 * p + 2];

    v4f o[8];

    // dense levels 0..4: recompute (tables 2.65 MB, chip-wide L2-hot).
#pragma unroll
    for (int lv = 0; lv < 5; ++lv) {
        const float m0 = mask[2 * lv], m1 = mask[2 * lv + 1];
        float r0 = 0.0f, r1 = 0.0f;
        if (m0 != 0.0f || m1 != 0.0f) {
            const int res = kRes[lv];
            int cx, cy, cz; float wx, wy, wz;
            corner_setup(px, py, pz, res, cx, cy, cz, wx, wy, wz);
            const float ux = 1.0f - wx, uy = 1.0f - wy, uz = 1.0f - wz;
            const float* __restrict__ tbl = table + (size_t)lv * (size_t)(kT * 2);
#pragma unroll
            for (int c = 0; c < 4; ++c) {
                const int dy = c & 1, dz = (c >> 1) & 1;
                const uint32_t idx0 =
                    (uint32_t)(cx + res * ((cy + dy) + res * (cz + dz)));
                // entries idx0 and idx0+1 are the two x-corners: one 16 B load
                v4f ab;
                __builtin_memcpy(&ab, tbl + 2u * idx0, sizeof(v4f));
                const float wyz = (dy ? wy : uy) * (dz ? wz : uz);
                const float w0 = ux * wyz, w1 = wx * wyz;
                r0 = fmaf(ab.x, w0, fmaf(ab.z, w1, r0));
                r1 = fmaf(ab.y, w0, fmaf(ab.w, w1, r1));
            }
            r0 *= m0; r1 *= m1;
        }
        if (lv & 1) { o[lv >> 1].z = r0; o[lv >> 1].w = r1; }
        else        { o[lv >> 1].x = r0; o[lv >> 1].y = r1; }
    }

    // hashed levels 5..15: read phase-1 results from ws.
#pragma unroll
    for (int lv = 5; lv < kNLevels; ++lv) {
        const float m0 = mask[2 * lv], m1 = mask[2 * lv + 1];
        float r0 = 0.0f, r1 = 0.0f;
        if (m0 != 0.0f || m1 != 0.0f) {
            const v2f v = __builtin_nontemporal_load(
                (const v2f*)(ws + ((size_t)(lv - 5) * n + p) * 2));
            r0 = v.x * m0;
            r1 = v.y * m1;
        }
        if (lv & 1) { o[lv >> 1].z = r0; o[lv >> 1].w = r1; }
        else        { o[lv >> 1].x = r0; o[lv >> 1].y = r1; }
    }

    v4f* __restrict__ op = (v4f*)(out + (size_t)p * 32);
#pragma unroll
    for (int i = 0; i < 8; ++i) op[i] = o[i];   // plain stores: L2 merges
}

// ---------- Fallback (R1 fused kernel) if ws is too small -------------------
__global__ __launch_bounds__(256) void fused_kernel(
    const float* __restrict__ x, const float* __restrict__ table,
    const float* __restrict__ mask, float* __restrict__ out, int n)
{
    const int p = blockIdx.x * blockDim.x + threadIdx.x;
    if (p >= n) return;
    const float px = x[3 * p + 0], py = x[3 * p + 1], pz = x[3 * p + 2];
    v4f o[8];
#pragma unroll
    for (int lv = 0; lv < kNLevels; ++lv) {
        const float m0 = mask[2 * lv], m1 = mask[2 * lv + 1];
        float r0 = 0.0f, r1 = 0.0f;
        if (m0 != 0.0f || m1 != 0.0f) {
            const int res = kRes[lv];
            const bool dense = ((long long)res * res * res) <= (long long)kT;
            int cx, cy, cz; float wx, wy, wz;
            corner_setup(px, py, pz, res, cx, cy, cz, wx, wy, wz);
            const float ux = 1.0f - wx, uy = 1.0f - wy, uz = 1.0f - wz;
            const float* __restrict__ tbl = table + (size_t)lv * (size_t)(kT * 2);
#pragma unroll
            for (int c = 0; c < 8; ++c) {
                const int dx = c & 1, dy = (c >> 1) & 1, dz = (c >> 2) & 1;
                const int ix = cx + dx, iy = cy + dy, iz = cz + dz;
                uint32_t idx;
                if (dense) idx = (uint32_t)(ix + res * (iy + res * iz));
                else idx = (((uint32_t)ix) ^ ((uint32_t)iy * kP1)
                                           ^ ((uint32_t)iz * kP2)) & (kT - 1u);
                const v2f v = *(const v2f*)(tbl + 2u * idx);
                const float w = (dx ? wx : ux) * (dy ? wy : uy) * (dz ? wz : uz);
                r0 = fmaf(v.x, w, r0);
                r1 = fmaf(v.y, w, r1);
            }
            r0 *= m0; r1 *= m1;
        }
        if (lv & 1) { o[lv >> 1].z = r0; o[lv >> 1].w = r1; }
        else        { o[lv >> 1].x = r0; o[lv >> 1].y = r1; }
    }
    v4f* __restrict__ op = (v4f*)(out + (size_t)p * 32);
#pragma unroll
    for (int i = 0; i < 8; ++i) op[i] = o[i];
}

}  // namespace

extern "C" void kernel_launch(void* const* d_in, const int* in_sizes, int n_in,
                              void* d_out, int out_size, void* d_ws, size_t ws_size,
                              hipStream_t stream) {
    const float* x     = (const float*)d_in[0];
    const float* table = (const float*)d_in[1];
    const float* mask  = (const float*)d_in[2];
    float*       out   = (float*)d_out;

    const int n = in_sizes[0] / 3;  // 1048576 points
    const int block = 256;
    const int gx = (n + block - 1) / block;

    const size_t ws_needed = (size_t)(kNLevels - 5) * (size_t)n * 2 * sizeof(float);
    if (ws_size >= ws_needed) {
        float* ws = (float*)d_ws;
        dim3 grid1(gx, kNLevels - 5);   // hashed levels 5..15 as y-slices
        hashed_level_kernel<<<grid1, block, 0, stream>>>(x, table, mask, ws, n);
        gather_out_kernel<<<gx, block, 0, stream>>>(x, table, ws, mask, out, n);
    } else {
        fused_kernel<<<gx, block, 0, stream>>>(x, table, mask, out, n);
    }
}